// Round 1
// 333.258 us; speedup vs baseline: 1.0214x; 1.0214x over previous
//
#include <hip/hip_runtime.h>
#include <cstdint>

// Top-k (k=384) along last axis (C=768) of [B=16, N=4096, C=768] fp32, scatter
// values back, zeros elsewhere. One wave (64 lanes) per row, 4 rows per block.
//
// v2: replace LDS-atomic 8-bit radix histograms (round-0 had ~768 same-address
// ds_atomic_adds into ~10 hot exponent bins per wave => serialized DS pipe)
// with a bitwise binary search on the monotone uint32 key:
//   per bit: 12x v_cmp vs wave-uniform SGPR candidate, counted via
//   __ballot (scalar mask) + s_bcnt1 on the SALU pipe (co-issues with VALU).
// Zero LDS, zero atomics, zero shuffles, zero barriers on the hot path.
// Values are reconstructed from keys (bijective map) to cut VGPR pressure.
// Tie-break = lowest index (matches jax.lax.top_k).

constexpr int C   = 768;
constexpr int TPB = 256;
constexpr int WPB = TPB / 64;  // 4 waves (rows) per block
constexpr int EPL = C / 64;    // 12 elements per lane
constexpr int NV  = EPL / 4;   // 3 float4 loads per lane

// Monotone bijection fp32 bits -> uint32 (larger float => larger key), then
// xor with flip (~0 for largest=0 so "largest key" = smallest float).
__device__ __forceinline__ uint32_t f2key(uint32_t b, uint32_t flip) {
    uint32_t m = (uint32_t)((int32_t)b >> 31) | 0x80000000u; // neg: ~b, pos: b|0x8000...
    return (b ^ m) ^ flip;
}
__device__ __forceinline__ float key2f(uint32_t key, uint32_t flip) {
    uint32_t u = key ^ flip;
    uint32_t m = (~(uint32_t)((int32_t)u >> 31)) | 0x80000000u;
    return __uint_as_float(u ^ m);
}

__global__ __launch_bounds__(TPB, 8) void topk_scatter_row(
        const float* __restrict__ x,
        const int*   __restrict__ pk,
        const int*   __restrict__ plg,
        float*       __restrict__ out,
        int rows) {
    const int lane = threadIdx.x & 63;
    const int wid  = threadIdx.x >> 6;
    const int row  = blockIdx.x * WPB + wid;
    if (row >= rows) return;

    const float* xr   = x   + (size_t)row * C;
    float*       orow = out + (size_t)row * C;

    const int      k    = pk[0];
    const uint32_t flip = (plg[0] != 0) ? 0u : 0xFFFFFFFFu;

    // element e = j*4+c lives at row index j*256 + lane*4 + c (coalesced float4)
    uint32_t key[EPL];
    #pragma unroll
    for (int j = 0; j < NV; ++j) {
        uint4 t = ((const uint4*)xr)[j * 64 + lane];
        key[j*4+0] = f2key(t.x, flip);
        key[j*4+1] = f2key(t.y, flip);
        key[j*4+2] = f2key(t.z, flip);
        key[j*4+3] = f2key(t.w, flip);
    }

    if (k <= 0) {
        #pragma unroll
        for (int j = 0; j < NV; ++j)
            ((float4*)orow)[j * 64 + lane] = make_float4(0.f, 0.f, 0.f, 0.f);
        return;
    }
    if (k >= C) {   // select everything
        #pragma unroll
        for (int j = 0; j < NV; ++j) {
            float4 o; float* oo = (float*)&o;
            #pragma unroll
            for (int c2 = 0; c2 < 4; ++c2) oo[c2] = key2f(key[j*4+c2], flip);
            ((float4*)orow)[j * 64 + lane] = o;
        }
        return;
    }

    // --- bitwise binary search for T = k-th largest key ---------------------
    // Invariant: count(key >= T) >= k. Final T is the k-th largest key value.
    uint32_t T = 0;
    bool exact = false;
    for (int b = 31; b >= 0; --b) {
        const uint32_t cand = T | (1u << b);
        int cnt = 0;
        #pragma unroll
        for (int e = 0; e < EPL; ++e)
            cnt += __popcll(__ballot(key[e] >= cand));
        if (cnt >= k) {
            T = cand;
            if (cnt == k) { exact = true; break; }  // whole set >= T is exactly k
        }
    }

    // --- build selection mask ----------------------------------------------
    uint32_t selmask = 0;
    if (exact) {
        #pragma unroll
        for (int e = 0; e < EPL; ++e)
            if (key[e] >= T) selmask |= 1u << e;
    } else {
        // duplicates of T straddle the boundary: take (k - count(>T)) of the
        // keys == T, lowest row-index first. Index order is (j, lane, c).
        int cgt = 0;
        #pragma unroll
        for (int e = 0; e < EPL; ++e) {
            if (key[e] > T) selmask |= 1u << e;
            cgt += __popcll(__ballot(key[e] > T));
        }
        const int need = k - cgt;  // >= 1 by construction
        const unsigned long long below = (1ull << lane) - 1ull;
        int base = 0;
        #pragma unroll
        for (int j = 0; j < NV; ++j) {
            int eq[4]; unsigned long long m[4];
            #pragma unroll
            for (int c2 = 0; c2 < 4; ++c2) {
                eq[c2] = (key[j*4+c2] == T) ? 1 : 0;
                m[c2]  = __ballot(eq[c2] != 0);
            }
            int lanebelow = 0;
            #pragma unroll
            for (int c2 = 0; c2 < 4; ++c2) lanebelow += __popcll(m[c2] & below);
            int own = 0;
            #pragma unroll
            for (int c2 = 0; c2 < 4; ++c2) {
                if (eq[c2] && (base + lanebelow + own) < need)
                    selmask |= 1u << (j*4 + c2);
                own += eq[c2];
            }
            #pragma unroll
            for (int c2 = 0; c2 < 4; ++c2) base += __popcll(m[c2]);
        }
    }

    // --- scatter values / zeros (coalesced float4) -------------------------
    #pragma unroll
    for (int j = 0; j < NV; ++j) {
        float4 o; float* oo = (float*)&o;
        #pragma unroll
        for (int c2 = 0; c2 < 4; ++c2) {
            const int e = j*4 + c2;
            oo[c2] = ((selmask >> e) & 1u) ? key2f(key[e], flip) : 0.0f;
        }
        ((float4*)orow)[j * 64 + lane] = o;
    }
}

extern "C" void kernel_launch(void* const* d_in, const int* in_sizes, int n_in,
                              void* d_out, int out_size, void* d_ws, size_t ws_size,
                              hipStream_t stream) {
    const float* x   = (const float*)d_in[0];
    const int*   pk  = (const int*)d_in[1];
    const int*   plg = (const int*)d_in[2];
    float*       out = (float*)d_out;

    const int rows   = in_sizes[0] / C;           // 16*4096 = 65536
    const int blocks = (rows + WPB - 1) / WPB;    // 16384
    topk_scatter_row<<<blocks, TPB, 0, stream>>>(x, pk, plg, out, rows);
}